// Round 8
// baseline (168.814 us; speedup 1.0000x reference)
//
#include <hip/hip_runtime.h>

#define BB 32
#define CC 768
#define SS 1024
#define LLn 77
#define DD 512
#define LP 80      // padded L for tlc rows / At rows
#define LP2 96     // padded L (K dim) for bf16 MFMA operands, mult of 32

#define RATIO 0.0751953125f   // 77/1024 exact in fp32

#define CVT_TXT_BLOCKS (BB * LP * DD / 4 / 256)   // 1280
#define CVT_W_BLOCKS ((CC / 32) * (DD / 32))      // 384
#define TG_BLOCKS (BB * 5 * 4)                    // 640

typedef short bf16x8 __attribute__((ext_vector_type(8)));
typedef float f32x4 __attribute__((ext_vector_type(4)));
typedef unsigned short u16;

__device__ __forceinline__ u16 f2bf(float f) {
    unsigned int u; __builtin_memcpy(&u, &f, 4);
    u += 0x7fffu + ((u >> 16) & 1u);   // RNE
    return (u16)(u >> 16);
}

// K0: tiny converts. text[b,77,512] f32 -> At[b,80,512] bf16 (pad rows zero);
//     W[d,c] f32 -> Wb[c,d] bf16 transposed.
__global__ __launch_bounds__(256) void k_cvt(const float* __restrict__ text,
                                             const float* __restrict__ Wt,
                                             u16* __restrict__ At,
                                             u16* __restrict__ Wb) {
    __shared__ float tile[32 * 33];
    const int bx = blockIdx.x;
    const int tid = threadIdx.x;
    if (bx < CVT_TXT_BLOCKS) {
        int j = bx * 256 + tid;                    // float4-granular, exact cover
        int row80 = j >> 7, col4 = (j & 127) << 2;
        int b = row80 / LP, l = row80 - b * LP;
        u16 o[4] = {0, 0, 0, 0};
        if (l < LLn) {
            float4 v = *reinterpret_cast<const float4*>(&text[((size_t)b * LLn + l) * DD + col4]);
            o[0] = f2bf(v.x); o[1] = f2bf(v.y); o[2] = f2bf(v.z); o[3] = f2bf(v.w);
        }
        *reinterpret_cast<uint2*>(&At[(size_t)row80 * DD + col4]) = *reinterpret_cast<uint2*>(o);
    } else {
        const int bw = bx - CVT_TXT_BLOCKS;
        const int c0 = (bw % (CC / 32)) * 32, d0 = (bw / (CC / 32)) * 32;
        const int tx = tid & 31, ty = tid >> 5;    // ty 0..7
#pragma unroll
        for (int k = 0; k < 4; ++k) {
            int d = ty + k * 8;
            tile[d * 33 + tx] = Wt[(size_t)(d0 + d) * CC + c0 + tx];
        }
        __syncthreads();
#pragma unroll
        for (int k = 0; k < 4; ++k) {
            int c = ty + k * 8;
            Wb[(size_t)(c0 + c) * DD + d0 + tx] = f2bf(tile[tx * 33 + c]);
        }
    }
}

// K1: t = text @ W, batch-aligned tiles. 640 blocks: bx -> (colgroup, b, tile).
__global__ __launch_bounds__(256) void k_tgemm(const u16* __restrict__ At,
                                               const u16* __restrict__ Wb,
                                               u16* __restrict__ tc,
                                               u16* __restrict__ tlc) {
    const int bx = blockIdx.x;
    const int tid = threadIdx.x;
    const int cg = bx / 160, mt = bx % 160;
    const int b = mt / 5, tile = mt % 5;
    const int l0 = tile * 16;
    const int w = tid >> 6, lane = tid & 63;
    const int lm = lane & 15, lg = lane >> 4;
    const int c0 = cg * 192 + w * 48;

    f32x4 acc[3];
#pragma unroll
    for (int nt = 0; nt < 3; ++nt) acc[nt] = (f32x4){0.f, 0.f, 0.f, 0.f};

    const u16* ap = At + ((size_t)b * LP + l0 + lm) * DD + lg * 8;
    const u16* bp = Wb + (size_t)(c0 + lm) * DD + lg * 8;
#pragma unroll 4
    for (int ks = 0; ks < 16; ++ks) {
        bf16x8 aq = *reinterpret_cast<const bf16x8*>(ap + ks * 32);
#pragma unroll
        for (int nt = 0; nt < 3; ++nt) {
            bf16x8 bv = *reinterpret_cast<const bf16x8*>(bp + (size_t)nt * 16 * DD + ks * 32);
            acc[nt] = __builtin_amdgcn_mfma_f32_16x16x32_bf16(aq, bv, acc[nt], 0, 0, 0);
        }
    }

    const int lq = l0 + lg * 4;   // quad start (pad rows produce zero acc)
#pragma unroll
    for (int nt = 0; nt < 3; ++nt) {
        int c = c0 + nt * 16 + lm;
        u16 pk[4];
#pragma unroll
        for (int r = 0; r < 4; ++r) pk[r] = f2bf(acc[nt][r]);
        uint2 pv; __builtin_memcpy(&pv, pk, 8);
        *reinterpret_cast<uint2*>(&tc[((size_t)b * CC + c) * LP2 + lq]) = pv;  // 8B aligned
#pragma unroll
        for (int r = 0; r < 4; ++r)
            tlc[((size_t)b * LP + lq + r) * CC + c] = pk[r];
    }
    if (tile == 4 && lg == 0) {   // zero tc K-pad l=80..95
        uint4 z = {0u, 0u, 0u, 0u};
#pragma unroll
        for (int nt = 0; nt < 3; ++nt) {
            int c = c0 + nt * 16 + lm;
            *reinterpret_cast<uint4*>(&tc[((size_t)b * CC + c) * LP2 + 80]) = z;
            *reinterpret_cast<uint4*>(&tc[((size_t)b * CC + c) * LP2 + 88]) = z;
        }
    }
}

// K2: fully fused: q (read ONCE) -> qh (LDS scatter) -> logits -> softmax -> PV -> out.
__global__ __launch_bounds__(256, 2) void k_fused(const u16* __restrict__ tc,
                                                  const u16* __restrict__ tlc,
                                                  const float* __restrict__ q,
                                                  const float* __restrict__ gamma,
                                                  float* __restrict__ out) {
    __shared__ float pmax[4][16];
    __shared__ float psum[4][16];
    __shared__ float qh_f32[16 * 80];              // 5120 B
    __shared__ u16 qh_bf[16 * 96];                 // 3072 B
    __shared__ float us[16 * 80];                  // 5120 B
    __shared__ __align__(16) char pbuf[4][6400];   // 25600 B: P bf16 [16][200] / u f32 [16][81]

    const int b = blockIdx.y;
    const int iBase = blockIdx.x * 16;
    const int tid = threadIdx.x;
    const int w = tid >> 6, lane = tid & 63;
    const int lm = lane & 15, lg = lane >> 4;
    const float g = gamma[0];

    // ---- 1. front-load this block's 16 q rows (the kernel's only big read) ----
    const size_t qBase = ((size_t)b * CC + iBase) * SS + (size_t)(tid << 2);
    f32x4 qreg[16];
#pragma unroll
    for (int r = 0; r < 16; ++r)
        qreg[r] = *reinterpret_cast<const f32x4*>(&q[qBase + (size_t)r * SS]);

    // ---- 2. zero the qh accumulator ----
    for (int i = tid; i < 16 * 80; i += 256) qh_f32[i] = 0.f;
    __syncthreads();

    // ---- 3. tent-weight scatter: qh[r][l] += A[s,l] * q[r][s] ----
    const int s0 = tid << 2;
    float wgt[4]; int i0k[4];
#pragma unroll
    for (int k = 0; k < 4; ++k) {
        float src = fmaf((float)(s0 + k) + 0.5f, RATIO, -0.5f);
        src = fminf(fmaxf(src, 0.f), 76.f);
        i0k[k] = (int)src;
        wgt[k] = src - (float)i0k[k];
    }
    const int la = i0k[0];    // i0 spans <=1 across the 4 s-values
#pragma unroll
    for (int r = 0; r < 16; ++r) {
        float c0 = 0.f, c1 = 0.f, c2 = 0.f;
#pragma unroll
        for (int k = 0; k < 4; ++k) {
            float qv = qreg[r][k];
            bool hi = (i0k[k] != la);
            float a0 = (1.f - wgt[k]) * qv, a1 = wgt[k] * qv;
            c0 += hi ? 0.f : a0;
            c1 += hi ? a0 : a1;
            c2 += hi ? a1 : 0.f;
        }
        atomicAdd(&qh_f32[r * 80 + la], c0);
        atomicAdd(&qh_f32[r * 80 + la + 1], c1);
        if (c2 != 0.f) atomicAdd(&qh_f32[r * 80 + la + 2], c2);
    }
    __syncthreads();

    // ---- 4. qh -> bf16 (scale folded), pad cols 77..95 zero ----
    for (int i = tid; i < 16 * 96; i += 256) {
        int row = i / 96, col = i - row * 96;
        float v = (col < LLn) ? qh_f32[row * 80 + col] * 0.03125f : 0.f;
        qh_bf[i] = f2bf(v);
    }
    __syncthreads();

    // ---- 5. logits: A = qh_bf rows, B = tc rows of this wave's 192-col j-slice ----
    bf16x8 aq0 = *reinterpret_cast<const bf16x8*>(&qh_bf[lm * 96 + lg * 8]);
    bf16x8 aq1 = *reinterpret_cast<const bf16x8*>(&qh_bf[lm * 96 + 32 + lg * 8]);
    bf16x8 aq2 = *reinterpret_cast<const bf16x8*>(&qh_bf[lm * 96 + 64 + lg * 8]);

    f32x4 acc[12];
#pragma unroll
    for (int t = 0; t < 12; ++t) acc[t] = (f32x4){0.f, 0.f, 0.f, 0.f};

    const u16* tcb = tc + ((size_t)b * CC + w * 192 + lm) * LP2 + lg * 8;
#pragma unroll
    for (int t = 0; t < 12; ++t) {
        const u16* p = tcb + (size_t)t * 16 * LP2;
        bf16x8 b0 = *reinterpret_cast<const bf16x8*>(p);
        bf16x8 b1 = *reinterpret_cast<const bf16x8*>(p + 32);
        bf16x8 b2 = *reinterpret_cast<const bf16x8*>(p + 64);
        acc[t] = __builtin_amdgcn_mfma_f32_16x16x32_bf16(aq0, b0, acc[t], 0, 0, 0);
        acc[t] = __builtin_amdgcn_mfma_f32_16x16x32_bf16(aq1, b1, acc[t], 0, 0, 0);
        acc[t] = __builtin_amdgcn_mfma_f32_16x16x32_bf16(aq2, b2, acc[t], 0, 0, 0);
    }

    // ---- 6. softmax (C layout: col = lane&15, row = lg*4 + reg) ----
    float m[4];
#pragma unroll
    for (int r = 0; r < 4; ++r) {
        float mm = acc[0][r];
#pragma unroll
        for (int t = 1; t < 12; ++t) mm = fmaxf(mm, acc[t][r]);
#pragma unroll
        for (int off = 8; off >= 1; off >>= 1) mm = fmaxf(mm, __shfl_xor(mm, off));
        m[r] = mm;
    }
    if (lm == 0) {
#pragma unroll
        for (int r = 0; r < 4; ++r) pmax[w][lg * 4 + r] = m[r];
    }
    __syncthreads();   // A: pmax visible
    float gm[4];
#pragma unroll
    for (int r = 0; r < 4; ++r) {
        int row = lg * 4 + r;
        gm[r] = fmaxf(fmaxf(pmax[0][row], pmax[1][row]), fmaxf(pmax[2][row], pmax[3][row]));
    }
    float s[4] = {0.f, 0.f, 0.f, 0.f};
#pragma unroll
    for (int t = 0; t < 12; ++t) {
#pragma unroll
        for (int r = 0; r < 4; ++r) {
            float e = __expf(acc[t][r] - gm[r]);
            acc[t][r] = e;
            s[r] += e;
        }
    }
#pragma unroll
    for (int r = 0; r < 4; ++r) {
#pragma unroll
        for (int off = 8; off >= 1; off >>= 1) s[r] += __shfl_xor(s[r], off);
    }
    if (lm == 0) {
#pragma unroll
        for (int r = 0; r < 4; ++r) psum[w][lg * 4 + r] = s[r];
    }

    // ---- 7. P -> bf16 into per-wave LDS (wave-private, no barrier) ----
    u16* P = (u16*)pbuf[w];
#pragma unroll
    for (int t = 0; t < 12; ++t) {
#pragma unroll
        for (int r = 0; r < 4; ++r)
            P[(lg * 4 + r) * 200 + t * 16 + lm] = f2bf(acc[t][r]);
    }

    // ---- 8. PV: u[16 x 80] += P[16 x 192] . tlc[192 x 80] ----
    f32x4 u[5];
#pragma unroll
    for (int nt = 0; nt < 5; ++nt) u[nt] = (f32x4){0.f, 0.f, 0.f, 0.f};
    const u16* tb = tlc + ((size_t)b * LP + lm) * CC + w * 192 + lg * 8;
#pragma unroll
    for (int ks = 0; ks < 6; ++ks) {
        bf16x8 pa = *reinterpret_cast<const bf16x8*>(&P[lm * 200 + ks * 32 + lg * 8]);
#pragma unroll
        for (int nt = 0; nt < 5; ++nt) {
            bf16x8 bv = *reinterpret_cast<const bf16x8*>(tb + (size_t)nt * 16 * CC + ks * 32);
            u[nt] = __builtin_amdgcn_mfma_f32_16x16x32_bf16(pa, bv, u[nt], 0, 0, 0);
        }
    }

    // ---- 9. cross-wave u reduce (alias P buffer) ----
    float* up = (float*)pbuf[w];
#pragma unroll
    for (int nt = 0; nt < 5; ++nt) {
#pragma unroll
        for (int r = 0; r < 4; ++r)
            up[(lg * 4 + r) * 81 + nt * 16 + lm] = u[nt][r];
    }
    __syncthreads();   // B: u partials + psum visible
#pragma unroll
    for (int k = 0; k < 5; ++k) {
        int idx = tid + (k << 8);
        int row = idx / LP, l = idx % LP;
        float v = ((float*)pbuf[0])[row * 81 + l] + ((float*)pbuf[1])[row * 81 + l]
                + ((float*)pbuf[2])[row * 81 + l] + ((float*)pbuf[3])[row * 81 + l];
        float denom = psum[0][row] + psum[1][row] + psum[2][row] + psum[3][row];
        us[row * LP + l] = v / denom;
    }
    __syncthreads();   // C: us ready

    // ---- 10. epilogue: out = qreg + gamma * interp(us), nontemporal stores ----
    int i1x[4];
#pragma unroll
    for (int k = 0; k < 4; ++k) i1x[k] = (i0k[k] < 76) ? i0k[k] + 1 : 76;
#pragma unroll
    for (int r = 0; r < 16; ++r) {
        const float* ur = &us[r * LP];
        f32x4 o;
#pragma unroll
        for (int k = 0; k < 4; ++k) {
            float uv = fmaf(1.f - wgt[k], ur[i0k[k]], wgt[k] * ur[i1x[k]]);
            o[k] = qreg[r][k] + g * uv;
        }
        __builtin_nontemporal_store(o, reinterpret_cast<f32x4*>(&out[qBase + (size_t)r * SS]));
    }
}

extern "C" void kernel_launch(void* const* d_in, const int* in_sizes, int n_in,
                              void* d_out, int out_size, void* d_ws, size_t ws_size,
                              hipStream_t stream) {
    const float* img   = (const float*)d_in[0];
    const float* text  = (const float*)d_in[1];
    const float* Wt    = (const float*)d_in[2];
    const float* gamma = (const float*)d_in[3];
    float* out = (float*)d_out;
    char* ws = (char*)d_ws;
    u16*   tc_bf  = (u16*)(ws);                   // 32*768*96*2 = 4,718,592
    u16*   tlc_bf = (u16*)(ws + 4718592);         // 32*80*768*2 = 3,932,160
    u16*   At_bf  = (u16*)(ws + 8650752);         // 32*80*512*2 = 2,621,440
    u16*   Wb_bf  = (u16*)(ws + 11272192);        // 768*512*2   =   786,432  (end 12,058,624)

    k_cvt<<<dim3(CVT_TXT_BLOCKS + CVT_W_BLOCKS), 256, 0, stream>>>(text, Wt, At_bf, Wb_bf);
    k_tgemm<<<dim3(TG_BLOCKS), 256, 0, stream>>>(At_bf, Wb_bf, tc_bf, tlc_bf);
    k_fused<<<dim3(48, BB), 256, 0, stream>>>(tc_bf, tlc_bf, img, gamma, out);
}

// Round 9
// 100.883 us; speedup vs baseline: 1.6734x; 1.6734x over previous
//
#include <hip/hip_runtime.h>

#define BB 32
#define CC 768
#define SS 1024
#define LLn 77
#define DD 512
#define LP 80      // padded L for tlc rows / At rows
#define LP2 96     // padded L (K dim) for bf16 MFMA operands, mult of 32

#define RATIO 0.0751953125f   // 77/1024 exact in fp32
#define IRATIO 13.298701f     // ~1024/77 (conservative loop bounds only)

#define CVT_TXT_BLOCKS (BB * LP * DD / 4 / 256)   // 1280
#define CVT_W_BLOCKS ((CC / 32) * (DD / 32))      // 384
#define TG_BLOCKS (BB * 5 * 4)                    // 640

typedef short bf16x8 __attribute__((ext_vector_type(8)));
typedef float f32x4 __attribute__((ext_vector_type(4)));
typedef unsigned short u16;

__device__ __forceinline__ float bf2f(unsigned int h16) {
    unsigned int u = h16 << 16;
    float f; __builtin_memcpy(&f, &u, 4); return f;
}
__device__ __forceinline__ u16 f2bf(float f) {
    unsigned int u; __builtin_memcpy(&u, &f, 4);
    u += 0x7fffu + ((u >> 16) & 1u);   // RNE
    return (u16)(u >> 16);
}

// K0: tiny converts. text[b,77,512] f32 -> At[b,80,512] bf16 (pad rows zero);
//     W[d,c] f32 -> Wb[c,d] bf16 transposed.
__global__ __launch_bounds__(256) void k_cvt(const float* __restrict__ text,
                                             const float* __restrict__ Wt,
                                             u16* __restrict__ At,
                                             u16* __restrict__ Wb) {
    __shared__ float tile[32 * 33];
    const int bx = blockIdx.x;
    const int tid = threadIdx.x;
    if (bx < CVT_TXT_BLOCKS) {
        int j = bx * 256 + tid;                    // float4-granular, exact cover
        int row80 = j >> 7, col4 = (j & 127) << 2;
        int b = row80 / LP, l = row80 - b * LP;
        u16 o[4] = {0, 0, 0, 0};
        if (l < LLn) {
            float4 v = *reinterpret_cast<const float4*>(&text[((size_t)b * LLn + l) * DD + col4]);
            o[0] = f2bf(v.x); o[1] = f2bf(v.y); o[2] = f2bf(v.z); o[3] = f2bf(v.w);
        }
        *reinterpret_cast<uint2*>(&At[(size_t)row80 * DD + col4]) = *reinterpret_cast<uint2*>(o);
    } else {
        const int bw = bx - CVT_TXT_BLOCKS;
        const int c0 = (bw % (CC / 32)) * 32, d0 = (bw / (CC / 32)) * 32;
        const int tx = tid & 31, ty = tid >> 5;    // ty 0..7
#pragma unroll
        for (int k = 0; k < 4; ++k) {
            int d = ty + k * 8;
            tile[d * 33 + tx] = Wt[(size_t)(d0 + d) * CC + c0 + tx];
        }
        __syncthreads();
#pragma unroll
        for (int k = 0; k < 4; ++k) {
            int c = ty + k * 8;
            Wb[(size_t)(c0 + c) * DD + d0 + tx] = f2bf(tile[tx * 33 + c]);
        }
    }
}

// K1: t = text @ W, batch-aligned tiles. 640 blocks: bx -> (colgroup, b, tile).
__global__ __launch_bounds__(256) void k_tgemm(const u16* __restrict__ At,
                                               const u16* __restrict__ Wb,
                                               u16* __restrict__ tc,
                                               u16* __restrict__ tlc) {
    const int bx = blockIdx.x;
    const int tid = threadIdx.x;
    const int cg = bx / 160, mt = bx % 160;
    const int b = mt / 5, tile = mt % 5;
    const int l0 = tile * 16;
    const int w = tid >> 6, lane = tid & 63;
    const int lm = lane & 15, lg = lane >> 4;
    const int c0 = cg * 192 + w * 48;

    f32x4 acc[3];
#pragma unroll
    for (int nt = 0; nt < 3; ++nt) acc[nt] = (f32x4){0.f, 0.f, 0.f, 0.f};

    const u16* ap = At + ((size_t)b * LP + l0 + lm) * DD + lg * 8;
    const u16* bp = Wb + (size_t)(c0 + lm) * DD + lg * 8;
#pragma unroll 4
    for (int ks = 0; ks < 16; ++ks) {
        bf16x8 aq = *reinterpret_cast<const bf16x8*>(ap + ks * 32);
#pragma unroll
        for (int nt = 0; nt < 3; ++nt) {
            bf16x8 bv = *reinterpret_cast<const bf16x8*>(bp + (size_t)nt * 16 * DD + ks * 32);
            acc[nt] = __builtin_amdgcn_mfma_f32_16x16x32_bf16(aq, bv, acc[nt], 0, 0, 0);
        }
    }

    const int lq = l0 + lg * 4;   // quad start (pad rows produce zero acc)
#pragma unroll
    for (int nt = 0; nt < 3; ++nt) {
        int c = c0 + nt * 16 + lm;
        u16 pk[4];
#pragma unroll
        for (int r = 0; r < 4; ++r) pk[r] = f2bf(acc[nt][r]);
        uint2 pv; __builtin_memcpy(&pv, pk, 8);
        *reinterpret_cast<uint2*>(&tc[((size_t)b * CC + c) * LP2 + lq]) = pv;  // 8B aligned
#pragma unroll
        for (int r = 0; r < 4; ++r)
            tlc[((size_t)b * LP + lq + r) * CC + c] = pk[r];
    }
    if (tile == 4 && lg == 0) {   // zero tc K-pad l=80..95
        uint4 z = {0u, 0u, 0u, 0u};
#pragma unroll
        for (int nt = 0; nt < 3; ++nt) {
            int c = c0 + nt * 16 + lm;
            *reinterpret_cast<uint4*>(&tc[((size_t)b * CC + c) * LP2 + 80]) = z;
            *reinterpret_cast<uint4*>(&tc[((size_t)b * CC + c) * LP2 + 88]) = z;
        }
    }
}

// K2: fully fused, q read ONCE. q -> LDS bf16 -> qh (tent GATHER, no atomics)
//     -> logits MFMA -> softmax -> PV MFMA -> out = q + gamma*interp(u).
__global__ __launch_bounds__(256, 2) void k_fused(const u16* __restrict__ tc,
                                                  const u16* __restrict__ tlc,
                                                  const float* __restrict__ q,
                                                  const float* __restrict__ gamma,
                                                  float* __restrict__ out) {
    // Aliased region: qlds[16][1024] bf16 (phases 1-2)  OVERLAYS  {pbuf, us, pmax, psum} (phases 3+).
    __shared__ __align__(16) char un[32768];
    u16* qlds = (u16*)un;                               // 32768 B, dead after gather sync
    char* pbufBase = un;                                // 4 x 6400 B per-wave P/u buffers
    float* us = (float*)(un + 25600);                   // 16*80*4 = 5120
    float* pmax = (float*)(un + 30720);                 // 4*16*4  = 256
    float* psum = (float*)(un + 30976);                 // 4*16*4  = 256  (end 31232)
    __shared__ u16 qh_bf[16 * 96];                      // 3072 B (separate; live from gather to MFMA)

    const int b = blockIdx.y;
    const int iBase = blockIdx.x * 16;
    const int tid = threadIdx.x;
    const int w = tid >> 6, lane = tid & 63;
    const int lm = lane & 15, lg = lane >> 4;
    const float g = gamma[0];

    // ---- 1. front-load this block's 16 q rows (the kernel's ONLY big read) ----
    const size_t qBase = ((size_t)b * CC + iBase) * SS + (size_t)(tid << 2);
    f32x4 qreg[16];
#pragma unroll
    for (int r = 0; r < 16; ++r)
        qreg[r] = *reinterpret_cast<const f32x4*>(&q[qBase + (size_t)r * SS]);
    const int s0 = tid << 2;
#pragma unroll
    for (int r = 0; r < 16; ++r) {
        u16 pk[4] = {f2bf(qreg[r][0]), f2bf(qreg[r][1]), f2bf(qreg[r][2]), f2bf(qreg[r][3])};
        uint2 pv; __builtin_memcpy(&pv, pk, 8);
        *reinterpret_cast<uint2*>(&qlds[r * 1024 + s0]) = pv;   // 8B, conflict-free
    }
    __syncthreads();   // qlds ready

    // ---- 2. tent GATHER: qh[r][l] = 0.03125 * sum_s tent(src(s)-l) * q[r][s] ----
#pragma unroll
    for (int k = 0; k < 5; ++k) {
        int e = tid + (k << 8);          // 16*80 = 1280 entries, 5 per thread
        int r = e / 80, l = e - r * 80;
        float val = 0.f;
        if (l < LLn) {
            int slo = max(0, (int)floorf(((float)l - 0.5f) * IRATIO - 0.5f) - 1);
            int shi = min(SS - 1, (int)ceilf(((float)l + 1.5f) * IRATIO - 0.5f) + 1);
            float fl = (float)l;
            float a = 0.f;
            for (int s = slo; s <= shi; ++s) {
                float src = fmaf((float)s + 0.5f, RATIO, -0.5f);
                src = fminf(fmaxf(src, 0.f), 76.f);
                float wgt = fmaxf(0.f, 1.f - fabsf(src - fl));   // tent == interp weight
                a = fmaf(wgt, bf2f(qlds[r * 1024 + s]), a);
            }
            val = a * 0.03125f;   // fold 1024^-0.5
        }
        qh_bf[r * 96 + l] = f2bf(val);
    }
    {   // zero qh pad cols 80..95
        int i = tid;
        if (i < 16 * 16) qh_bf[(i >> 4) * 96 + 80 + (i & 15)] = 0;
    }
    __syncthreads();   // qh_bf ready; qlds now DEAD -> union free for pmax/psum/pbuf/us

    // ---- 3. logits: A = qh_bf rows, B = tc rows of this wave's 192-col j-slice ----
    bf16x8 aq0 = *reinterpret_cast<const bf16x8*>(&qh_bf[lm * 96 + lg * 8]);
    bf16x8 aq1 = *reinterpret_cast<const bf16x8*>(&qh_bf[lm * 96 + 32 + lg * 8]);
    bf16x8 aq2 = *reinterpret_cast<const bf16x8*>(&qh_bf[lm * 96 + 64 + lg * 8]);

    f32x4 acc[12];
#pragma unroll
    for (int t = 0; t < 12; ++t) acc[t] = (f32x4){0.f, 0.f, 0.f, 0.f};

    const u16* tcb = tc + ((size_t)b * CC + w * 192 + lm) * LP2 + lg * 8;
#pragma unroll
    for (int t = 0; t < 12; ++t) {
        const u16* p = tcb + (size_t)t * 16 * LP2;
        bf16x8 b0 = *reinterpret_cast<const bf16x8*>(p);
        bf16x8 b1 = *reinterpret_cast<const bf16x8*>(p + 32);
        bf16x8 b2 = *reinterpret_cast<const bf16x8*>(p + 64);
        acc[t] = __builtin_amdgcn_mfma_f32_16x16x32_bf16(aq0, b0, acc[t], 0, 0, 0);
        acc[t] = __builtin_amdgcn_mfma_f32_16x16x32_bf16(aq1, b1, acc[t], 0, 0, 0);
        acc[t] = __builtin_amdgcn_mfma_f32_16x16x32_bf16(aq2, b2, acc[t], 0, 0, 0);
    }

    // ---- 4. softmax (C layout: col = lane&15, row = lg*4 + reg) ----
    float m[4];
#pragma unroll
    for (int r = 0; r < 4; ++r) {
        float mm = acc[0][r];
#pragma unroll
        for (int t = 1; t < 12; ++t) mm = fmaxf(mm, acc[t][r]);
#pragma unroll
        for (int off = 8; off >= 1; off >>= 1) mm = fmaxf(mm, __shfl_xor(mm, off));
        m[r] = mm;
    }
    if (lm == 0) {
#pragma unroll
        for (int r = 0; r < 4; ++r) pmax[w * 16 + lg * 4 + r] = m[r];
    }
    __syncthreads();   // A: pmax visible
    float gm[4];
#pragma unroll
    for (int r = 0; r < 4; ++r) {
        int row = lg * 4 + r;
        gm[r] = fmaxf(fmaxf(pmax[row], pmax[16 + row]), fmaxf(pmax[32 + row], pmax[48 + row]));
    }
    float s[4] = {0.f, 0.f, 0.f, 0.f};
#pragma unroll
    for (int t = 0; t < 12; ++t) {
#pragma unroll
        for (int r = 0; r < 4; ++r) {
            float e = __expf(acc[t][r] - gm[r]);
            acc[t][r] = e;
            s[r] += e;
        }
    }
#pragma unroll
    for (int r = 0; r < 4; ++r) {
#pragma unroll
        for (int off = 8; off >= 1; off >>= 1) s[r] += __shfl_xor(s[r], off);
    }
    if (lm == 0) {
#pragma unroll
        for (int r = 0; r < 4; ++r) psum[w * 16 + lg * 4 + r] = s[r];
    }

    // ---- 5. P -> bf16 into per-wave LDS (wave-private, no barrier) ----
    u16* P = (u16*)(pbufBase + w * 6400);
#pragma unroll
    for (int t = 0; t < 12; ++t) {
#pragma unroll
        for (int r = 0; r < 4; ++r)
            P[(lg * 4 + r) * 200 + t * 16 + lm] = f2bf(acc[t][r]);
    }

    // ---- 6. PV: u[16 x 80] += P[16 x 192] . tlc[192 x 80] ----
    f32x4 u[5];
#pragma unroll
    for (int nt = 0; nt < 5; ++nt) u[nt] = (f32x4){0.f, 0.f, 0.f, 0.f};
    const u16* tb = tlc + ((size_t)b * LP + lm) * CC + w * 192 + lg * 8;
#pragma unroll
    for (int ks = 0; ks < 6; ++ks) {
        bf16x8 pa = *reinterpret_cast<const bf16x8*>(&P[lm * 200 + ks * 32 + lg * 8]);
#pragma unroll
        for (int nt = 0; nt < 5; ++nt) {
            bf16x8 bv = *reinterpret_cast<const bf16x8*>(tb + (size_t)nt * 16 * CC + ks * 32);
            u[nt] = __builtin_amdgcn_mfma_f32_16x16x32_bf16(pa, bv, u[nt], 0, 0, 0);
        }
    }

    // ---- 7. cross-wave u reduce (alias P buffer; wave-local reuse is ordered) ----
    float* up = (float*)(pbufBase + w * 6400);
#pragma unroll
    for (int nt = 0; nt < 5; ++nt) {
#pragma unroll
        for (int r = 0; r < 4; ++r)
            up[(lg * 4 + r) * 81 + nt * 16 + lm] = u[nt][r];
    }
    __syncthreads();   // B: u partials + psum visible
#pragma unroll
    for (int k = 0; k < 5; ++k) {
        int idx = tid + (k << 8);
        int row = idx / LP, l = idx - row * LP;
        float v = ((float*)(pbufBase))[row * 81 + l]
                + ((float*)(pbufBase + 6400))[row * 81 + l]
                + ((float*)(pbufBase + 12800))[row * 81 + l]
                + ((float*)(pbufBase + 19200))[row * 81 + l];
        float denom = psum[row] + psum[16 + row] + psum[32 + row] + psum[48 + row];
        us[row * LP + l] = v / denom;
    }
    __syncthreads();   // C: us ready

    // ---- 8. epilogue: out = qreg + gamma * interp(us), nontemporal stores ----
    float wgt[4]; int i0k[4], i1x[4];
#pragma unroll
    for (int k = 0; k < 4; ++k) {
        float src = fmaf((float)(s0 + k) + 0.5f, RATIO, -0.5f);
        src = fminf(fmaxf(src, 0.f), 76.f);
        i0k[k] = (int)src;
        wgt[k] = src - (float)i0k[k];
        i1x[k] = (i0k[k] < 76) ? i0k[k] + 1 : 76;
    }
#pragma unroll
    for (int r = 0; r < 16; ++r) {
        const float* ur = &us[r * LP];
        f32x4 o;
#pragma unroll
        for (int k = 0; k < 4; ++k) {
            float uv = fmaf(1.f - wgt[k], ur[i0k[k]], wgt[k] * ur[i1x[k]]);
            o[k] = qreg[r][k] + g * uv;
        }
        __builtin_nontemporal_store(o, reinterpret_cast<f32x4*>(&out[qBase + (size_t)r * SS]));
    }
}

extern "C" void kernel_launch(void* const* d_in, const int* in_sizes, int n_in,
                              void* d_out, int out_size, void* d_ws, size_t ws_size,
                              hipStream_t stream) {
    const float* img   = (const float*)d_in[0];
    const float* text  = (const float*)d_in[1];
    const float* Wt    = (const float*)d_in[2];
    const float* gamma = (const float*)d_in[3];
    float* out = (float*)d_out;
    char* ws = (char*)d_ws;
    u16*   tc_bf  = (u16*)(ws);                   // 32*768*96*2 = 4,718,592
    u16*   tlc_bf = (u16*)(ws + 4718592);         // 32*80*768*2 = 3,932,160
    u16*   At_bf  = (u16*)(ws + 8650752);         // 32*80*512*2 = 2,621,440
    u16*   Wb_bf  = (u16*)(ws + 11272192);        // 768*512*2   =   786,432  (end 12,058,624)

    k_cvt<<<dim3(CVT_TXT_BLOCKS + CVT_W_BLOCKS), 256, 0, stream>>>(text, Wt, At_bf, Wb_bf);
    k_tgemm<<<dim3(TG_BLOCKS), 256, 0, stream>>>(At_bf, Wb_bf, tc_bf, tlc_bf);
    k_fused<<<dim3(48, BB), 256, 0, stream>>>(tc_bf, tlc_bf, img, gamma, out);
}